// Round 14
// baseline (200.905 us; speedup 1.0000x reference)
//
#include <hip/hip_runtime.h>

// AdaIN on MI355X — 4-dispatch pipeline, MFMA segment reduction.
// content: (Nc=1e6, C=64) f32, style: (2.5e5, 64) f32, B=16 segments.
// R11 proved segment-sum-as-MFMA (S=E^T·X, Q=E^T·X²); R13 proved staging vs
// direct loads is neutral -> in-flight bytes not the limiter. R14 theory:
// block-private contiguous streams (2048 of them) thrash HBM; grid-stride
// the row tiles so the whole grid sweeps one moving window (the pattern
// fillBuffer/apply achieve 6-7 TB/s with). Apply iterates windows in REVERSE
// to harvest L3-resident content tail left by the reduce.
// memset -> mfma reduce -> finalize -> apply.

#define NB 16          // num_batches
#define NC 64          // channels
#define NREP 16        // global partial-buffer replicas
#define CBLKS 1638     // content blocks } 2048 total = 8 blocks/CU
#define SBLKS 410      // style blocks   }

typedef float fvec4 __attribute__((ext_vector_type(4)));   // nontemporal-ok
typedef float f32x4 __attribute__((ext_vector_type(4)));
typedef short bf16x8 __attribute__((ext_vector_type(8)));

// ws float-offset layout:
#define WS_CPART 0                        // NREP * 2048 (sum[1024], sumsq[1024])
#define WS_SPART (NREP * 2048)            // NREP * 2048
#define WS_CCNT  (2 * NREP * 2048)        // NREP * 16
#define WS_SCNT  (WS_CCNT + NREP * NB)    // NREP * 16
#define WS_SCALE (WS_SCNT + NREP * NB)    // 1024
#define WS_BIAS  (WS_SCALE + 1024)        // 1024
#define WS_ZERO_FLOATS WS_SCALE

__device__ __forceinline__ unsigned cvtpk(float lo, float hi)
{
    unsigned r;
    asm("v_cvt_pk_bf16_f32 %0, %1, %2" : "=v"(r) : "v"(lo), "v"(hi));
    return r;
}

__device__ __forceinline__ void reduce_body(
    const float* __restrict__ feats, const int* __restrict__ idx, int nrows,
    float* __restrict__ part, float* __restrict__ cntp,
    int blk, int nblk, int tid, float* lsum /*2048*/)
{
    const int lane = tid & 63;
    const int wv   = tid >> 6;             // wave = channel-quarter
    const int half = lane >> 4;            // k-group 0..3
    const int sub  = lane & 15;            // A-row (batch) / B-col (channel)

    f32x4 accS = {0, 0, 0, 0}, accQ = {0, 0, 0, 0};
    int cnti = 0;

    const int ntiles = (nrows + 31) >> 5;  // 32-row tiles

    // Grid-stride over tiles: all blocks sweep one moving ~16MB window.
    for (int t = blk; t < ntiles; t += nblk) {
        const int rb = t << 5;
        const int rl = rb + (lane & 31);
        const int vidx = (rl < nrows) ? idx[rl] : -1;   // -1 pad: one-hot row 0

        // ---- counts (wave 0; lanes 0-31 carry the tile's rows) ----
        if (wv == 0) {
            #pragma unroll
            for (int b = 0; b < NB; ++b) {
                const unsigned long long m = __ballot(vidx == b) & 0xFFFFFFFFull;
                cnti += (lane == b) ? (int)__popcll(m) : 0;
            }
        }

        // ---- A fragment: one-hot E^T, elem j -> k = half*8+j, m = sub ----
        union { unsigned w[4]; bf16x8 v; } A;
        const int kb4 = half * 32;
        #pragma unroll
        for (int i = 0; i < 4; ++i) {
            const int k0 = __builtin_amdgcn_ds_bpermute(kb4 + 8 * i,     vidx);
            const int k1 = __builtin_amdgcn_ds_bpermute(kb4 + 8 * i + 4, vidx);
            const unsigned lo = (k0 == sub) ? 0x3F80u     : 0u;   // bf16(1.0)
            const unsigned hi = (k1 == sub) ? 0x3F800000u : 0u;
            A.w[i] = lo | hi;
        }

        // ---- B values: X[rb + half*8 + j][wv*16 + sub] (this wave's quarter) ----
        float xv[8];
        #pragma unroll
        for (int j = 0; j < 8; ++j) {
            int r = rb + half * 8 + j;
            if (r > nrows - 1) r = nrows - 1;           // A=0 kills padded rows
            xv[j] = feats[(size_t)r * NC + wv * 16 + sub];
        }

        union { unsigned w[4]; bf16x8 v; } Bs, Bq;
        #pragma unroll
        for (int i = 0; i < 4; ++i) {
            const float a0 = xv[2 * i], a1 = xv[2 * i + 1];
            Bs.w[i] = cvtpk(a0, a1);
            Bq.w[i] = cvtpk(a0 * a0, a1 * a1);
        }

        accS = __builtin_amdgcn_mfma_f32_16x16x32_bf16(A.v, Bs.v, accS, 0, 0, 0);
        accQ = __builtin_amdgcn_mfma_f32_16x16x32_bf16(A.v, Bq.v, accQ, 0, 0, 0);
    }

    // ---- merge: wave owns channels [wv*16, wv*16+16) exclusively ----
    // D layout (HW-verified R11): col = sub, row(batch) = half*4 + reg.
    #pragma unroll
    for (int i = 0; i < 4; ++i) {
        const int m = half * 4 + i;
        lsum[m * NC + wv * 16 + sub]        = accS[i];
        lsum[1024 + m * NC + wv * 16 + sub] = accQ[i];
    }
    __syncthreads();
    float* dst = part + (blk & (NREP - 1)) * 2048;
    for (int i = tid; i < 2048; i += 256)
        atomicAdd(&dst[i], lsum[i]);
    if (wv == 0 && lane < NB)
        atomicAdd(&cntp[(blk & (NREP - 1)) * NB + lane], (float)cnti);
}

__global__ __launch_bounds__(256) void reduce_stats(
    const float* __restrict__ content, const int* __restrict__ ci, int Nc,
    const float* __restrict__ style,   const int* __restrict__ si, int Ns,
    float* __restrict__ ws)
{
    __shared__ float lsum[2048];           // 8 KB merge buffer
    if (blockIdx.x < CBLKS)
        reduce_body(content, ci, Nc, ws + WS_CPART, ws + WS_CCNT,
                    blockIdx.x, CBLKS, threadIdx.x, lsum);
    else
        reduce_body(style, si, Ns, ws + WS_SPART, ws + WS_SCNT,
                    blockIdx.x - CBLKS, SBLKS, threadIdx.x, lsum);
}

__global__ void finalize_kernel(float* __restrict__ ws)
{
    if (threadIdx.x >= NC) return;
    const int c = threadIdx.x;
    const float* c_part = ws + WS_CPART;
    const float* s_part = ws + WS_SPART;
    const float* c_cntp = ws + WS_CCNT;
    const float* s_cntp = ws + WS_SCNT;
    float* scale = ws + WS_SCALE;
    float* bias  = ws + WS_BIAS;

    float gm = 0.f, gs = 0.f;
    for (int b = 0; b < NB; ++b) {
        float csum = 0.f, csq = 0.f, ssum = 0.f, ssq = 0.f, ccnt = 0.f, scnt = 0.f;
        #pragma unroll
        for (int rep = 0; rep < NREP; ++rep) {
            csum += c_part[rep * 2048 + b * NC + c];
            csq  += c_part[rep * 2048 + 1024 + b * NC + c];
            ssum += s_part[rep * 2048 + b * NC + c];
            ssq  += s_part[rep * 2048 + 1024 + b * NC + c];
            ccnt += c_cntp[rep * NB + b];
            scnt += s_cntp[rep * NB + b];
        }
        const float smean = ssum / scnt;
        const float svar  = (ssq - scnt * smean * smean) / (scnt - 1.0f);
        const float sstd  = sqrtf(fmaxf(svar, 0.f)) + 1e-8f;
        if (b == 0) { gm = smean; gs = sstd; }
        else        { gm = 0.9f * gm + 0.1f * smean; gs = 0.9f * gs + 0.1f * sstd; }
        const float cmean = csum / ccnt;
        const float cvar  = (csq - ccnt * cmean * cmean) / (ccnt - 1.0f);
        const float cstd  = sqrtf(fmaxf(cvar, 0.f)) + 1e-8f;
        const float sc = gs / cstd;        // out = sc*x + bi
        scale[b * NC + c] = sc;
        bias [b * NC + c] = gm - sc * cmean;
    }
}

__global__ __launch_bounds__(256) void apply_kernel(
    const float* __restrict__ content, const int* __restrict__ ci, int Nc,
    const float* __restrict__ ws, fvec4* __restrict__ out4)
{
    __shared__ fvec4 s_sc[NB * 17];        // stride-17 pad
    __shared__ fvec4 s_bi[NB * 17];
    const fvec4* scale4 = (const fvec4*)(ws + WS_SCALE);
    const fvec4* bias4  = (const fvec4*)(ws + WS_BIAS);
    for (int i = threadIdx.x; i < NB * 16; i += 256) {
        const int b = i >> 4, c4 = i & 15;
        s_sc[b * 17 + c4] = scale4[i];
        s_bi[b * 17 + c4] = bias4[i];
    }
    __syncthreads();

    const fvec4* feats4 = (const fvec4*)content;
    const int total4 = Nc * 16;
    const int stride = gridDim.x * 256;
    const int nsteps = (total4 + stride - 1) / stride;
    // Reverse window order: the content TAIL is L3-resident after the reduce.
    for (int s = nsteps - 1; s >= 0; --s) {
        const int i = s * stride + blockIdx.x * 256 + threadIdx.x;
        if (i >= total4) continue;
        const int r  = i >> 4;
        const int c4 = i & 15;
        const int b  = ci[r];
        const fvec4 v  = feats4[i];
        const fvec4 sc = s_sc[b * 17 + c4];
        const fvec4 bi = s_bi[b * 17 + c4];
        fvec4 o;
        o.x = fmaf(sc.x, v.x, bi.x);
        o.y = fmaf(sc.y, v.y, bi.y);
        o.z = fmaf(sc.z, v.z, bi.z);
        o.w = fmaf(sc.w, v.w, bi.w);
        __builtin_nontemporal_store(o, &out4[i]);
    }
}

extern "C" void kernel_launch(void* const* d_in, const int* in_sizes, int n_in,
                              void* d_out, int out_size, void* d_ws, size_t ws_size,
                              hipStream_t stream)
{
    const float* content = (const float*)d_in[0];
    const float* style   = (const float*)d_in[1];
    const int*   ci      = (const int*)d_in[2];
    const int*   si      = (const int*)d_in[3];

    const int Nc = in_sizes[0] / NC;   // 1,000,000
    const int Ns = in_sizes[1] / NC;   //   250,000

    float* ws = (float*)d_ws;
    // ws never re-poisoned between replays: zero accumulators every call.
    (void)hipMemsetAsync(ws, 0, WS_ZERO_FLOATS * sizeof(float), stream);

    reduce_stats<<<CBLKS + SBLKS, 256, 0, stream>>>(content, ci, Nc, style, si, Ns, ws);
    finalize_kernel<<<1, 64, 0, stream>>>(ws);
    apply_kernel<<<2048, 256, 0, stream>>>(content, ci, Nc, ws, (fvec4*)d_out);
}

// Round 15
// 200.122 us; speedup vs baseline: 1.0039x; 1.0039x over previous
//
#include <hip/hip_runtime.h>

// AdaIN on MI355X — 4-dispatch pipeline, MFMA segment reduction.
// content: (Nc=1e6, C=64) f32, style: (2.5e5, 64) f32, B=16 segments.
// R11: full-tile/wave MFMA reduce, 12 waves/CU -> 184.4 total (best).
// R13: staged quartered, 32 waves/CU -> 186.0 (staging neutral).
// R14: quartered + grid-stride + reverse apply -> 200.9 (regressed; bundled).
// R15 unbundles: quartered low-VGPR reduce, BLOCK-CHUNKED tiles (R13 tiling),
// direct dword loads (no staging), FORWARD apply. Isolates occupancy effect.
// memset -> mfma reduce -> finalize -> apply.

#define NB 16          // num_batches
#define NC 64          // channels
#define NREP 16        // global partial-buffer replicas
#define CBLKS 1638     // content blocks } 2048 total = 8 blocks/CU
#define SBLKS 410      // style blocks   }

typedef float fvec4 __attribute__((ext_vector_type(4)));   // nontemporal-ok
typedef float f32x4 __attribute__((ext_vector_type(4)));
typedef short bf16x8 __attribute__((ext_vector_type(8)));

// ws float-offset layout:
#define WS_CPART 0                        // NREP * 2048 (sum[1024], sumsq[1024])
#define WS_SPART (NREP * 2048)            // NREP * 2048
#define WS_CCNT  (2 * NREP * 2048)        // NREP * 16
#define WS_SCNT  (WS_CCNT + NREP * NB)    // NREP * 16
#define WS_SCALE (WS_SCNT + NREP * NB)    // 1024
#define WS_BIAS  (WS_SCALE + 1024)        // 1024
#define WS_ZERO_FLOATS WS_SCALE

__device__ __forceinline__ unsigned cvtpk(float lo, float hi)
{
    unsigned r;
    asm("v_cvt_pk_bf16_f32 %0, %1, %2" : "=v"(r) : "v"(lo), "v"(hi));
    return r;
}

__device__ __forceinline__ void reduce_body(
    const float* __restrict__ feats, const int* __restrict__ idx, int nrows,
    float* __restrict__ part, float* __restrict__ cntp,
    int blk, int nblk, int tid, float* lsum /*2048*/)
{
    const int lane = tid & 63;
    const int wv   = tid >> 6;             // wave = channel-quarter
    const int half = lane >> 4;            // k-group 0..3
    const int sub  = lane & 15;            // A-row (batch) / B-col (channel)

    f32x4 accS = {0, 0, 0, 0}, accQ = {0, 0, 0, 0};
    int cnti = 0;

    const int ntiles = (nrows + 31) >> 5;  // 32-row tiles
    const int tpb = (ntiles + nblk - 1) / nblk;
    const int t0 = blk * tpb;
    const int t1 = (t0 + tpb < ntiles) ? (t0 + tpb) : ntiles;

    for (int t = t0; t < t1; ++t) {
        const int rb = t << 5;
        const int rl = rb + (lane & 31);
        const int vidx = (rl < nrows) ? idx[rl] : -1;   // -1 pad: one-hot row 0

        // ---- counts (wave 0; lanes 0-31 carry the tile's rows) ----
        if (wv == 0) {
            #pragma unroll
            for (int b = 0; b < NB; ++b) {
                const unsigned long long m = __ballot(vidx == b) & 0xFFFFFFFFull;
                cnti += (lane == b) ? (int)__popcll(m) : 0;
            }
        }

        // ---- A fragment: one-hot E^T, elem j -> k = half*8+j, m = sub ----
        union { unsigned w[4]; bf16x8 v; } A;
        const int kb4 = half * 32;
        #pragma unroll
        for (int i = 0; i < 4; ++i) {
            const int k0 = __builtin_amdgcn_ds_bpermute(kb4 + 8 * i,     vidx);
            const int k1 = __builtin_amdgcn_ds_bpermute(kb4 + 8 * i + 4, vidx);
            const unsigned lo = (k0 == sub) ? 0x3F80u     : 0u;   // bf16(1.0)
            const unsigned hi = (k1 == sub) ? 0x3F800000u : 0u;
            A.w[i] = lo | hi;
        }

        // ---- B values: X[rb + half*8 + j][wv*16 + sub] (this wave's quarter) ----
        float xv[8];
        #pragma unroll
        for (int j = 0; j < 8; ++j) {
            int r = rb + half * 8 + j;
            if (r > nrows - 1) r = nrows - 1;           // A=0 kills padded rows
            xv[j] = feats[(size_t)r * NC + wv * 16 + sub];
        }

        union { unsigned w[4]; bf16x8 v; } Bs, Bq;
        #pragma unroll
        for (int i = 0; i < 4; ++i) {
            const float a0 = xv[2 * i], a1 = xv[2 * i + 1];
            Bs.w[i] = cvtpk(a0, a1);
            Bq.w[i] = cvtpk(a0 * a0, a1 * a1);
        }

        accS = __builtin_amdgcn_mfma_f32_16x16x32_bf16(A.v, Bs.v, accS, 0, 0, 0);
        accQ = __builtin_amdgcn_mfma_f32_16x16x32_bf16(A.v, Bq.v, accQ, 0, 0, 0);
    }

    // ---- merge: wave owns channels [wv*16, wv*16+16) exclusively ----
    // D layout (HW-verified R11): col = sub, row(batch) = half*4 + reg.
    #pragma unroll
    for (int i = 0; i < 4; ++i) {
        const int m = half * 4 + i;
        lsum[m * NC + wv * 16 + sub]        = accS[i];
        lsum[1024 + m * NC + wv * 16 + sub] = accQ[i];
    }
    __syncthreads();
    float* dst = part + (blk & (NREP - 1)) * 2048;
    for (int i = tid; i < 2048; i += 256)
        atomicAdd(&dst[i], lsum[i]);
    if (wv == 0 && lane < NB)
        atomicAdd(&cntp[(blk & (NREP - 1)) * NB + lane], (float)cnti);
}

__global__ __launch_bounds__(256) void reduce_stats(
    const float* __restrict__ content, const int* __restrict__ ci, int Nc,
    const float* __restrict__ style,   const int* __restrict__ si, int Ns,
    float* __restrict__ ws)
{
    __shared__ float lsum[2048];           // 8 KB merge buffer
    if (blockIdx.x < CBLKS)
        reduce_body(content, ci, Nc, ws + WS_CPART, ws + WS_CCNT,
                    blockIdx.x, CBLKS, threadIdx.x, lsum);
    else
        reduce_body(style, si, Ns, ws + WS_SPART, ws + WS_SCNT,
                    blockIdx.x - CBLKS, SBLKS, threadIdx.x, lsum);
}

__global__ void finalize_kernel(float* __restrict__ ws)
{
    if (threadIdx.x >= NC) return;
    const int c = threadIdx.x;
    const float* c_part = ws + WS_CPART;
    const float* s_part = ws + WS_SPART;
    const float* c_cntp = ws + WS_CCNT;
    const float* s_cntp = ws + WS_SCNT;
    float* scale = ws + WS_SCALE;
    float* bias  = ws + WS_BIAS;

    float gm = 0.f, gs = 0.f;
    for (int b = 0; b < NB; ++b) {
        float csum = 0.f, csq = 0.f, ssum = 0.f, ssq = 0.f, ccnt = 0.f, scnt = 0.f;
        #pragma unroll
        for (int rep = 0; rep < NREP; ++rep) {
            csum += c_part[rep * 2048 + b * NC + c];
            csq  += c_part[rep * 2048 + 1024 + b * NC + c];
            ssum += s_part[rep * 2048 + b * NC + c];
            ssq  += s_part[rep * 2048 + 1024 + b * NC + c];
            ccnt += c_cntp[rep * NB + b];
            scnt += s_cntp[rep * NB + b];
        }
        const float smean = ssum / scnt;
        const float svar  = (ssq - scnt * smean * smean) / (scnt - 1.0f);
        const float sstd  = sqrtf(fmaxf(svar, 0.f)) + 1e-8f;
        if (b == 0) { gm = smean; gs = sstd; }
        else        { gm = 0.9f * gm + 0.1f * smean; gs = 0.9f * gs + 0.1f * sstd; }
        const float cmean = csum / ccnt;
        const float cvar  = (csq - ccnt * cmean * cmean) / (ccnt - 1.0f);
        const float cstd  = sqrtf(fmaxf(cvar, 0.f)) + 1e-8f;
        const float sc = gs / cstd;        // out = sc*x + bi
        scale[b * NC + c] = sc;
        bias [b * NC + c] = gm - sc * cmean;
    }
}

__global__ __launch_bounds__(256) void apply_kernel(
    const float* __restrict__ content, const int* __restrict__ ci, int Nc,
    const float* __restrict__ ws, fvec4* __restrict__ out4)
{
    __shared__ fvec4 s_sc[NB * 17];        // stride-17 pad
    __shared__ fvec4 s_bi[NB * 17];
    const fvec4* scale4 = (const fvec4*)(ws + WS_SCALE);
    const fvec4* bias4  = (const fvec4*)(ws + WS_BIAS);
    for (int i = threadIdx.x; i < NB * 16; i += 256) {
        const int b = i >> 4, c4 = i & 15;
        s_sc[b * 17 + c4] = scale4[i];
        s_bi[b * 17 + c4] = bias4[i];
    }
    __syncthreads();

    const fvec4* feats4 = (const fvec4*)content;
    const int total4 = Nc * 16;
    const int stride = gridDim.x * 256;
    for (int i = blockIdx.x * 256 + threadIdx.x; i < total4; i += stride) {
        const int r  = i >> 4;
        const int c4 = i & 15;
        const int b  = ci[r];
        const fvec4 v  = feats4[i];
        const fvec4 sc = s_sc[b * 17 + c4];
        const fvec4 bi = s_bi[b * 17 + c4];
        fvec4 o;
        o.x = fmaf(sc.x, v.x, bi.x);
        o.y = fmaf(sc.y, v.y, bi.y);
        o.z = fmaf(sc.z, v.z, bi.z);
        o.w = fmaf(sc.w, v.w, bi.w);
        __builtin_nontemporal_store(o, &out4[i]);
    }
}

extern "C" void kernel_launch(void* const* d_in, const int* in_sizes, int n_in,
                              void* d_out, int out_size, void* d_ws, size_t ws_size,
                              hipStream_t stream)
{
    const float* content = (const float*)d_in[0];
    const float* style   = (const float*)d_in[1];
    const int*   ci      = (const int*)d_in[2];
    const int*   si      = (const int*)d_in[3];

    const int Nc = in_sizes[0] / NC;   // 1,000,000
    const int Ns = in_sizes[1] / NC;   //   250,000

    float* ws = (float*)d_ws;
    // ws never re-poisoned between replays: zero accumulators every call.
    (void)hipMemsetAsync(ws, 0, WS_ZERO_FLOATS * sizeof(float), stream);

    reduce_stats<<<CBLKS + SBLKS, 256, 0, stream>>>(content, ci, Nc, style, si, Ns, ws);
    finalize_kernel<<<1, 64, 0, stream>>>(ws);
    apply_kernel<<<2048, 256, 0, stream>>>(content, ci, Nc, ws, (fvec4*)d_out);
}

// Round 16
// 182.224 us; speedup vs baseline: 1.1025x; 1.0982x over previous
//
#include <hip/hip_runtime.h>

// AdaIN on MI355X — 4-dispatch pipeline, MFMA segment reduction.
// content: (Nc=1e6, C=64) f32, style: (2.5e5, 64) f32, B=16 segments.
// Reduce = segment-sum-as-MFMA (S=E^T·X, Q=E^T·X², one-hot A from idx).
// R16 = R13 perfected: coalesced global_load_lds staging with SOURCE-side
// XOR swizzle (dest linear, m173) so the ds_read side is bank-conflict-free
// (2-way max = free), double-buffered tiles -> ONE barrier per tile, and
// 24KB LDS -> 6 blocks/CU for cross-block latency hiding.
// memset -> mfma reduce -> finalize -> apply.

#define NB 16          // num_batches
#define NC 64          // channels
#define NREP 16        // global partial-buffer replicas
#define CBLKS 1228     // content blocks } 1536 total = 6 blocks/CU
#define SBLKS 308      // style blocks   } (~26 tiles per block both)

typedef float fvec4 __attribute__((ext_vector_type(4)));   // nontemporal-ok
typedef float f32x4 __attribute__((ext_vector_type(4)));
typedef short bf16x8 __attribute__((ext_vector_type(8)));

// ws float-offset layout:
#define WS_CPART 0                        // NREP * 2048 (sum[1024], sumsq[1024])
#define WS_SPART (NREP * 2048)            // NREP * 2048
#define WS_CCNT  (2 * NREP * 2048)        // NREP * 16
#define WS_SCNT  (WS_CCNT + NREP * NB)    // NREP * 16
#define WS_SCALE (WS_SCNT + NREP * NB)    // 1024
#define WS_BIAS  (WS_SCALE + 1024)        // 1024
#define WS_ZERO_FLOATS WS_SCALE

__device__ __forceinline__ unsigned cvtpk(float lo, float hi)
{
    unsigned r;
    asm("v_cvt_pk_bf16_f32 %0, %1, %2" : "=v"(r) : "v"(lo), "v"(hi));
    return r;
}

__device__ __forceinline__ void gload16(const float* g, float* l)
{
    // async global->LDS, 16B/lane; LDS dest = base + lane*16 (linear).
    __builtin_amdgcn_global_load_lds(
        (const __attribute__((address_space(1))) void*)g,
        (__attribute__((address_space(3))) void*)l, 16, 0, 0);
}

// Stage tile t into bufp (2048 floats). Wave wv issues instrs {2wv, 2wv+1}.
// LDS float (row, c4') holds global (rb+row, ch4 = c4' ^ 2*(row>>3)):
// source-side swizzle, linear dest (m173). Read side: conflict-free 2-way.
__device__ __forceinline__ void stage_tile(
    const float* __restrict__ feats, int nrows, int rb, int wv, int lane,
    float* bufp)
{
    #pragma unroll
    for (int u = 0; u < 2; ++u) {
        const int i = 2 * wv + u;
        int rg = rb + i * 4 + (lane >> 4);
        if (rg > nrows - 1) rg = nrows - 1;            // pad rows unused (A=0)
        const int c4 = (lane & 15) ^ (2 * ((i >> 1) & 3));
        gload16(feats + (size_t)rg * NC + c4 * 4, bufp + i * 256);
    }
}

__device__ __forceinline__ void reduce_body(
    const float* __restrict__ feats, const int* __restrict__ idx, int nrows,
    float* __restrict__ part, float* __restrict__ cntp,
    int blk, int nblk, int tid, float* buf /*2*2048*/, float* lsum /*2048*/)
{
    const int lane = tid & 63;
    const int wv   = tid >> 6;             // wave = channel-quarter
    const int half = lane >> 4;            // k-group 0..3
    const int sub  = lane & 15;            // A-row (batch) / B-col (channel)

    f32x4 accS = {0, 0, 0, 0}, accQ = {0, 0, 0, 0};
    int cnti = 0;

    const int ntiles = (nrows + 31) >> 5;  // 32-row tiles
    const int tpb = (ntiles + nblk - 1) / nblk;
    const int t0 = blk * tpb;
    const int t1 = (t0 + tpb < ntiles) ? (t0 + tpb) : ntiles;

    // swizzled ds_read base for this lane (float index), +j*64 per element
    const int c4p   = (wv * 4 + (sub >> 2)) ^ (2 * half);
    const int rbase = half * 8 * NC + c4p * 4 + (sub & 3);

    int vidx = -1;
    if (t0 < t1) {
        stage_tile(feats, nrows, t0 << 5, wv, lane, buf);
        const int rl = (t0 << 5) + (lane & 31);
        vidx = (rl < nrows) ? idx[rl] : -1;
    }

    int cur = 0;
    for (int t = t0; t < t1; ++t) {
        __syncthreads();                   // drains vmcnt -> buf[cur] staged

        // issue next tile's staging immediately (flies across reads+MFMA)
        if (t + 1 < t1)
            stage_tile(feats, nrows, (t + 1) << 5, wv, lane, buf + (cur ^ 1) * 2048);
        int vn = -1;
        if (t + 1 < t1) {
            const int rl = ((t + 1) << 5) + (lane & 31);
            vn = (rl < nrows) ? idx[rl] : -1;
        }

        // ---- counts (wave 0; lanes 0-31 carry the tile's rows) ----
        if (wv == 0) {
            #pragma unroll
            for (int b = 0; b < NB; ++b) {
                const unsigned long long m = __ballot(vidx == b) & 0xFFFFFFFFull;
                cnti += (lane == b) ? (int)__popcll(m) : 0;
            }
        }

        // ---- A fragment: one-hot E^T, elem pair (2i,2i+1), k = half*8+.. ----
        union { unsigned w[4]; bf16x8 v; } A;
        const int kb4 = half * 32;
        #pragma unroll
        for (int i = 0; i < 4; ++i) {
            const int k0 = __builtin_amdgcn_ds_bpermute(kb4 + 8 * i,     vidx);
            const int k1 = __builtin_amdgcn_ds_bpermute(kb4 + 8 * i + 4, vidx);
            const unsigned lo = (k0 == sub) ? 0x3F80u     : 0u;   // bf16(1.0)
            const unsigned hi = (k1 == sub) ? 0x3F800000u : 0u;
            A.w[i] = lo | hi;
        }

        // ---- B from LDS (swizzled, conflict-free): elem j = X[..][wv*16+sub] ----
        const float* bp = buf + cur * 2048;
        float xv[8];
        #pragma unroll
        for (int j = 0; j < 8; ++j)
            xv[j] = bp[rbase + j * NC];

        union { unsigned w[4]; bf16x8 v; } Bs, Bq;
        #pragma unroll
        for (int i = 0; i < 4; ++i) {
            const float a0 = xv[2 * i], a1 = xv[2 * i + 1];
            Bs.w[i] = cvtpk(a0, a1);
            Bq.w[i] = cvtpk(a0 * a0, a1 * a1);
        }

        accS = __builtin_amdgcn_mfma_f32_16x16x32_bf16(A.v, Bs.v, accS, 0, 0, 0);
        accQ = __builtin_amdgcn_mfma_f32_16x16x32_bf16(A.v, Bq.v, accQ, 0, 0, 0);

        vidx = vn;
        cur ^= 1;
    }

    // ---- merge: wave owns channels [wv*16, wv*16+16) exclusively ----
    // D layout (HW-verified R11): col = sub, row(batch) = half*4 + reg.
    #pragma unroll
    for (int i = 0; i < 4; ++i) {
        const int m = half * 4 + i;
        lsum[m * NC + wv * 16 + sub]        = accS[i];
        lsum[1024 + m * NC + wv * 16 + sub] = accQ[i];
    }
    __syncthreads();
    float* dst = part + (blk & (NREP - 1)) * 2048;
    for (int i = tid; i < 2048; i += 256)
        atomicAdd(&dst[i], lsum[i]);
    if (wv == 0 && lane < NB)
        atomicAdd(&cntp[(blk & (NREP - 1)) * NB + lane], (float)cnti);
}

__global__ __launch_bounds__(256) void reduce_stats(
    const float* __restrict__ content, const int* __restrict__ ci, int Nc,
    const float* __restrict__ style,   const int* __restrict__ si, int Ns,
    float* __restrict__ ws)
{
    __shared__ float buf[2 * 2048];        // 16 KB double-buffered tiles
    __shared__ float lsum[2048];           // 8 KB merge buffer
    if (blockIdx.x < CBLKS)
        reduce_body(content, ci, Nc, ws + WS_CPART, ws + WS_CCNT,
                    blockIdx.x, CBLKS, threadIdx.x, buf, lsum);
    else
        reduce_body(style, si, Ns, ws + WS_SPART, ws + WS_SCNT,
                    blockIdx.x - CBLKS, SBLKS, threadIdx.x, buf, lsum);
}

__global__ void finalize_kernel(float* __restrict__ ws)
{
    if (threadIdx.x >= NC) return;
    const int c = threadIdx.x;
    const float* c_part = ws + WS_CPART;
    const float* s_part = ws + WS_SPART;
    const float* c_cntp = ws + WS_CCNT;
    const float* s_cntp = ws + WS_SCNT;
    float* scale = ws + WS_SCALE;
    float* bias  = ws + WS_BIAS;

    float gm = 0.f, gs = 0.f;
    for (int b = 0; b < NB; ++b) {
        float csum = 0.f, csq = 0.f, ssum = 0.f, ssq = 0.f, ccnt = 0.f, scnt = 0.f;
        #pragma unroll
        for (int rep = 0; rep < NREP; ++rep) {
            csum += c_part[rep * 2048 + b * NC + c];
            csq  += c_part[rep * 2048 + 1024 + b * NC + c];
            ssum += s_part[rep * 2048 + b * NC + c];
            ssq  += s_part[rep * 2048 + 1024 + b * NC + c];
            ccnt += c_cntp[rep * NB + b];
            scnt += s_cntp[rep * NB + b];
        }
        const float smean = ssum / scnt;
        const float svar  = (ssq - scnt * smean * smean) / (scnt - 1.0f);
        const float sstd  = sqrtf(fmaxf(svar, 0.f)) + 1e-8f;
        if (b == 0) { gm = smean; gs = sstd; }
        else        { gm = 0.9f * gm + 0.1f * smean; gs = 0.9f * gs + 0.1f * sstd; }
        const float cmean = csum / ccnt;
        const float cvar  = (csq - ccnt * cmean * cmean) / (ccnt - 1.0f);
        const float cstd  = sqrtf(fmaxf(cvar, 0.f)) + 1e-8f;
        const float sc = gs / cstd;        // out = sc*x + bi
        scale[b * NC + c] = sc;
        bias [b * NC + c] = gm - sc * cmean;
    }
}

__global__ __launch_bounds__(256) void apply_kernel(
    const float* __restrict__ content, const int* __restrict__ ci, int Nc,
    const float* __restrict__ ws, fvec4* __restrict__ out4)
{
    __shared__ fvec4 s_sc[NB * 17];        // stride-17 pad
    __shared__ fvec4 s_bi[NB * 17];
    const fvec4* scale4 = (const fvec4*)(ws + WS_SCALE);
    const fvec4* bias4  = (const fvec4*)(ws + WS_BIAS);
    for (int i = threadIdx.x; i < NB * 16; i += 256) {
        const int b = i >> 4, c4 = i & 15;
        s_sc[b * 17 + c4] = scale4[i];
        s_bi[b * 17 + c4] = bias4[i];
    }
    __syncthreads();

    const fvec4* feats4 = (const fvec4*)content;
    const int total4 = Nc * 16;
    const int stride = gridDim.x * 256;
    for (int i = blockIdx.x * 256 + threadIdx.x; i < total4; i += stride) {
        const int r  = i >> 4;
        const int c4 = i & 15;
        const int b  = ci[r];
        const fvec4 v  = feats4[i];
        const fvec4 sc = s_sc[b * 17 + c4];
        const fvec4 bi = s_bi[b * 17 + c4];
        fvec4 o;
        o.x = fmaf(sc.x, v.x, bi.x);
        o.y = fmaf(sc.y, v.y, bi.y);
        o.z = fmaf(sc.z, v.z, bi.z);
        o.w = fmaf(sc.w, v.w, bi.w);
        __builtin_nontemporal_store(o, &out4[i]);
    }
}

extern "C" void kernel_launch(void* const* d_in, const int* in_sizes, int n_in,
                              void* d_out, int out_size, void* d_ws, size_t ws_size,
                              hipStream_t stream)
{
    const float* content = (const float*)d_in[0];
    const float* style   = (const float*)d_in[1];
    const int*   ci      = (const int*)d_in[2];
    const int*   si      = (const int*)d_in[3];

    const int Nc = in_sizes[0] / NC;   // 1,000,000
    const int Ns = in_sizes[1] / NC;   //   250,000

    float* ws = (float*)d_ws;
    // ws never re-poisoned between replays: zero accumulators every call.
    (void)hipMemsetAsync(ws, 0, WS_ZERO_FLOATS * sizeof(float), stream);

    reduce_stats<<<CBLKS + SBLKS, 256, 0, stream>>>(content, ci, Nc, style, si, Ns, ws);
    finalize_kernel<<<1, 64, 0, stream>>>(ws);
    apply_kernel<<<2048, 256, 0, stream>>>(content, ci, Nc, ws, (fvec4*)d_out);
}